// Round 7
// baseline (1324.234 us; speedup 1.0000x reference)
//
#include <hip/hip_runtime.h>
#include <hip/hip_fp16.h>
#include <stdint.h>

// Int8Linear: y[m,n] = fp16round((sum_k x[m,k] * (fp16)W[n,k]) * scale[n]).
// Wire dtypes: x fp32, weight int32, scale fp32, out fp32 (fp16 values).
// M=8192, K=4096, N=11008.
// Round 7: (a) M-fastest-within-XCD tile mapping (B panel L2-resident per
// XCD, A L3-resident -> fetch ~160MB ideal); (b) full-tile prefetch distance:
// stage B(t+2)@P3, A(t+2)@P4, vmcnt(8) waits only on iter-old loads.

typedef _Float16 half8 __attribute__((ext_vector_type(8)));
typedef _Float16 half4 __attribute__((ext_vector_type(4)));
typedef float floatx4 __attribute__((ext_vector_type(4)));

constexpr int Mdim = 8192;
constexpr int Ndim = 11008;
constexpr int Kdim = 4096;
constexpr int BM = 256, BN = 256, BK = 64;
constexpr int NT = Kdim / BK;   // 64
constexpr int GX = Ndim / BN;   // 43
constexpr int GY = Mdim / BM;   // 32
constexpr int NWG = GX * GY;    // 1376 (%8==0 -> simple XCD swizzle bijective)
constexpr int PER_XCD = NWG / 8;

#define GLD16(gp, lp) __builtin_amdgcn_global_load_lds(                        \
    (const __attribute__((address_space(1))) void*)(gp),                       \
    (__attribute__((address_space(3))) void*)(lp), 16, 0, 0)

__device__ inline half4 cvt4i(int4 a) {
  half4 h;
  h[0] = (_Float16)a.x; h[1] = (_Float16)a.y; h[2] = (_Float16)a.z; h[3] = (_Float16)a.w;
  return h;
}
__device__ inline half4 cvt4f(float4 a) {
  half4 h;
  h[0] = (_Float16)a.x; h[1] = (_Float16)a.y; h[2] = (_Float16)a.z; h[3] = (_Float16)a.w;
  return h;
}
__device__ inline half8 cvt_i8(int4 a, int4 b) {
  half8 h;
  h[0] = (_Float16)a.x; h[1] = (_Float16)a.y; h[2] = (_Float16)a.z; h[3] = (_Float16)a.w;
  h[4] = (_Float16)b.x; h[5] = (_Float16)b.y; h[6] = (_Float16)b.z; h[7] = (_Float16)b.w;
  return h;
}
__device__ inline half8 cvt_f8(float4 a, float4 b) {
  half8 h;
  h[0] = (_Float16)a.x; h[1] = (_Float16)a.y; h[2] = (_Float16)a.z; h[3] = (_Float16)a.w;
  h[4] = (_Float16)b.x; h[5] = (_Float16)b.y; h[6] = (_Float16)b.z; h[7] = (_Float16)b.w;
  return h;
}

// -------- merged pre-pass, fully coalesced: thread i <-> 16B chunk i --------
constexpr int CONVB_TOT = 4096;
constexpr int WBLK = 2340;  // ~57% of blocks for W (270MB of 471MB traffic)
__global__ __launch_bounds__(256) void conv_both(const int* __restrict__ w,
                                                 const float* __restrict__ x,
                                                 _Float16* __restrict__ wo,
                                                 _Float16* __restrict__ xo) {
  if (blockIdx.x < WBLK) {
    const long n4 = (long)Ndim * Kdim / 4;       // int4 chunks
    const long stride = (long)WBLK * 256;
    const int4* __restrict__ src = (const int4*)w;
    half4* __restrict__ dst = (half4*)wo;
    for (long i = (long)blockIdx.x * 256 + threadIdx.x; i < n4; i += stride)
      dst[i] = cvt4i(src[i]);
  } else {
    const long n4 = (long)Mdim * Kdim / 4;       // float4 chunks
    const long stride = (long)(CONVB_TOT - WBLK) * 256;
    const float4* __restrict__ src = (const float4*)x;
    half4* __restrict__ dst = (half4*)xo;
    for (long i = (long)(blockIdx.x - WBLK) * 256 + threadIdx.x; i < n4; i += stride)
      dst[i] = cvt4f(src[i]);
  }
}

// ---------------- 256x256 8-phase GEMM ----------------
// 512 threads = 8 waves (2M x 4N); per-wave C = 128x64 = acc[8][4] frags.
// LDS: 2 bufs x (A 32KB + B 32KB) = 128KB, [256][64] f16 rows of 128B.
// Swizzle: byte ^= ((row&7)<<4); staging source col = 8*((l&7)^(l>>3))
// (inverse within-row permutation; proven conflict-free, R6: conflicts=0).
// Tile map: M-fastest within XCD -> each XCD's concurrent blocks share ONE
// B panel (2MB, L2-resident); A streams via L3 (67MB, resident).
// Schedule per K-tile t (tile t lives in slot t&1 for both A and B):
//   P1: read A(t,mh0) 8x + B(t,np0) 4x                | mfma q0
//   P2: read B(t,np1) 4x   [B(t) fully read]          | mfma q1
//   P3: read A(t,mh1) 8x | stage B(t+2)->Bslot[t&1]   | mfma q2  [A(t) done]
//   P4:                  | stage A(t+2)->Aslot[t&1]   | mfma q3
//       vmcnt(8) -- waits only tile-(t+1) loads (issued one full iter ago),
//       leaves tile-(t+2)'s 8 in flight. Never stalls in steady state.
// Race-safety: stage into a region only after the barrier that follows the
// phase in which that region's last reads were lgkmcnt(0)-drained.
__global__ __launch_bounds__(512, 2) void gemm8(
    const _Float16* __restrict__ Xh, const _Float16* __restrict__ Wh,
    const float* __restrict__ scale, float* __restrict__ Y) {
  __shared__ _Float16 lds[2][2][BM * BK];  // [buf][A=0/B=1][256*64] = 128 KB

  const int tid = threadIdx.x;
  const int lane = tid & 63;
  const int wave = tid >> 6;   // 0..7
  const int wr = wave >> 2;    // 0..1 (M)
  const int wcn = wave & 3;    // 0..3 (N)

  const int bid = blockIdx.x;
  const int swz = (bid & 7) * PER_XCD + (bid >> 3);
  const int bm0 = (swz % GY) * BM;   // M-fastest within XCD
  const int bn0 = (swz / GY) * BN;

  const _Float16* Ag = Xh + (size_t)bm0 * Kdim;
  const _Float16* Bg = Wh + (size_t)bn0 * Kdim;

  // staging source coords (inverse of (row&7)<<4 byte swizzle)
  const int srow = (wave << 3) + (lane >> 3);                 // +h*128+r*64
  const int scol = ((lane & 7) ^ (lane >> 3)) << 3;           // f16 elements

  auto stage = [&](int buf, int op, int h, int t) {
    const _Float16* G = op ? Bg : Ag;
    const int kt = t * BK;
#pragma unroll
    for (int r = 0; r < 2; ++r) {
      const _Float16* src = G + (size_t)(h * 128 + r * 64 + srow) * Kdim + kt + scol;
      char* dst = (char*)&lds[buf][op][0] + h * 16384 + r * 8192 + (wave << 10);
      GLD16(src, dst);  // HW adds lane*16 to wave-uniform dst
    }
  };
  auto ldsRd = [&](int buf, int op, int row, int cb) -> half8 {
    int b = row * 128 + cb;
    b ^= (row & 7) << 4;  // 3-bit slot rotation
    return *(const half8*)((const char*)&lds[buf][op][0] + b);
  };

  floatx4 acc[8][4] = {};

  // ---- prologue: tile0 (A,B) then tile1 (A,B); vmcnt(8) = tile0 resident --
  stage(0, 0, 0, 0); stage(0, 0, 1, 0);
  stage(0, 1, 0, 0); stage(0, 1, 1, 0);
  stage(1, 0, 0, 1); stage(1, 0, 1, 1);
  stage(1, 1, 0, 1); stage(1, 1, 1, 1);
  asm volatile("s_waitcnt vmcnt(8)" ::: "memory");
  __builtin_amdgcn_s_barrier();

  for (int t = 0; t < NT; ++t) {
    const int cur = t & 1;
    const bool do2 = (t + 2 < NT);
    half8 af[8], bf[2][4];
    const int cb0 = (lane >> 4) * 16;  // k-slice byte base per lane

    // ================ P1: quad (mh0, np0), 12 ds_reads ================
#pragma unroll
    for (int m2 = 0; m2 < 4; ++m2)
#pragma unroll
      for (int ks = 0; ks < 2; ++ks)
        af[m2 * 2 + ks] = ldsRd(cur, 0, wr * 128 + m2 * 16 + (lane & 15), ks * 64 + cb0);
#pragma unroll
    for (int n2 = 0; n2 < 2; ++n2)
#pragma unroll
      for (int ks = 0; ks < 2; ++ks)
        bf[0][n2 * 2 + ks] = ldsRd(cur, 1, wcn * 64 + n2 * 16 + (lane & 15), ks * 64 + cb0);
    asm volatile("s_waitcnt lgkmcnt(8)" ::: "memory");
    __builtin_amdgcn_s_barrier();
    asm volatile("s_waitcnt lgkmcnt(0)" ::: "memory");
    __builtin_amdgcn_s_setprio(1);
#pragma unroll
    for (int m2 = 0; m2 < 4; ++m2)
#pragma unroll
      for (int n2 = 0; n2 < 2; ++n2)
#pragma unroll
        for (int ks = 0; ks < 2; ++ks)
          acc[m2][n2] = __builtin_amdgcn_mfma_f32_16x16x32_f16(
              af[m2 * 2 + ks], bf[0][n2 * 2 + ks], acc[m2][n2], 0, 0, 0);
    __builtin_amdgcn_s_setprio(0);
    __builtin_amdgcn_s_barrier();

    // ================ P2: quad (mh0, np1), 4 ds_reads ================
#pragma unroll
    for (int n2 = 0; n2 < 2; ++n2)
#pragma unroll
      for (int ks = 0; ks < 2; ++ks)
        bf[1][n2 * 2 + ks] =
            ldsRd(cur, 1, wcn * 64 + 32 + n2 * 16 + (lane & 15), ks * 64 + cb0);
    __builtin_amdgcn_s_barrier();
    asm volatile("s_waitcnt lgkmcnt(0)" ::: "memory");
    __builtin_amdgcn_s_setprio(1);
#pragma unroll
    for (int m2 = 0; m2 < 4; ++m2)
#pragma unroll
      for (int n2 = 0; n2 < 2; ++n2)
#pragma unroll
        for (int ks = 0; ks < 2; ++ks)
          acc[m2][2 + n2] = __builtin_amdgcn_mfma_f32_16x16x32_f16(
              af[m2 * 2 + ks], bf[1][n2 * 2 + ks], acc[m2][2 + n2], 0, 0, 0);
    __builtin_amdgcn_s_setprio(0);
    __builtin_amdgcn_s_barrier();  // B(t) region now free

    // ================ P3: quad (mh1, np0), 8 ds_reads + stage B(t+2) =====
#pragma unroll
    for (int m2 = 0; m2 < 4; ++m2)
#pragma unroll
      for (int ks = 0; ks < 2; ++ks)
        af[m2 * 2 + ks] =
            ldsRd(cur, 0, wr * 128 + 64 + m2 * 16 + (lane & 15), ks * 64 + cb0);
    if (do2) { stage(cur, 1, 0, t + 2); stage(cur, 1, 1, t + 2); }
    __builtin_amdgcn_s_barrier();
    asm volatile("s_waitcnt lgkmcnt(0)" ::: "memory");
    __builtin_amdgcn_s_setprio(1);
#pragma unroll
    for (int m2 = 0; m2 < 4; ++m2)
#pragma unroll
      for (int n2 = 0; n2 < 2; ++n2)
#pragma unroll
        for (int ks = 0; ks < 2; ++ks)
          acc[4 + m2][n2] = __builtin_amdgcn_mfma_f32_16x16x32_f16(
              af[m2 * 2 + ks], bf[0][n2 * 2 + ks], acc[4 + m2][n2], 0, 0, 0);
    __builtin_amdgcn_s_setprio(0);
    __builtin_amdgcn_s_barrier();  // A(t) region now free

    // ================ P4: quad (mh1, np1), stage A(t+2) ================
    if (do2) { stage(cur, 0, 0, t + 2); stage(cur, 0, 1, t + 2); }
    __builtin_amdgcn_s_barrier();
    __builtin_amdgcn_s_setprio(1);
#pragma unroll
    for (int m2 = 0; m2 < 4; ++m2)
#pragma unroll
      for (int n2 = 0; n2 < 2; ++n2)
#pragma unroll
        for (int ks = 0; ks < 2; ++ks)
          acc[4 + m2][2 + n2] = __builtin_amdgcn_mfma_f32_16x16x32_f16(
              af[m2 * 2 + ks], bf[1][n2 * 2 + ks], acc[4 + m2][2 + n2], 0, 0, 0);
    __builtin_amdgcn_s_setprio(0);
    if (do2) {
      asm volatile("s_waitcnt vmcnt(8)" ::: "memory");  // drain t+1, keep t+2
    } else {
      asm volatile("s_waitcnt vmcnt(0)" ::: "memory");  // tail drain
    }
    __builtin_amdgcn_s_barrier();
  }

  // ---- epilogue: fp16round(acc * scale[n]) stored as fp32 ----
  float sc[4];
#pragma unroll
  for (int ni = 0; ni < 4; ++ni)
    sc[ni] = scale[bn0 + wcn * 64 + ni * 16 + (lane & 15)];
#pragma unroll
  for (int mi = 0; mi < 8; ++mi) {
    const int row0 = bm0 + wr * 128 + mi * 16 + (lane >> 4) * 4;
#pragma unroll
    for (int ni = 0; ni < 4; ++ni) {
      const int col = bn0 + wcn * 64 + ni * 16 + (lane & 15);
#pragma unroll
      for (int i = 0; i < 4; ++i)
        Y[(size_t)(row0 + i) * Ndim + col] = (float)(_Float16)(acc[mi][ni][i] * sc[ni]);
    }
  }
}

// ---------------- fallback (ws too small): fused-convert 128^2 ----------------
__global__ __launch_bounds__(256) void gemm_fused(
    const float* __restrict__ Xf, const int* __restrict__ W32,
    const float* __restrict__ scale, float* __restrict__ Y) {
  constexpr int bM = 128, bN = 128, bK = 64;
  __shared__ _Float16 As[bM * bK];
  __shared__ _Float16 Bs[bN * bK];
  const int tid = threadIdx.x, lane = tid & 63, wave = tid >> 6;
  const int wr2 = wave >> 1, wc2 = wave & 1;
  const int bn0 = (int)(blockIdx.x % (Ndim / bN)) * bN;
  const int bm0 = (int)(blockIdx.x / (Ndim / bN)) * bM;
  floatx4 acc[4][4] = {};
  for (int t = 0; t < Kdim / bK; ++t) {
    const int kt = t * bK;
    {
      const int e0 = tid << 5, row = e0 >> 6, col = e0 & 63;
      const float* gp = Xf + (size_t)(bm0 + row) * Kdim + kt + col;
      half8* lp = (half8*)&As[row * bK + col];
#pragma unroll
      for (int v = 0; v < 4; ++v)
        lp[v] = cvt_f8(((const float4*)gp)[2 * v], ((const float4*)gp)[2 * v + 1]);
      const int* gq = W32 + (size_t)(bn0 + row) * Kdim + kt + col;
      half8* lq = (half8*)&Bs[row * bK + col];
#pragma unroll
      for (int v = 0; v < 4; ++v)
        lq[v] = cvt_i8(((const int4*)gq)[2 * v], ((const int4*)gq)[2 * v + 1]);
    }
    __syncthreads();
#pragma unroll
    for (int ks = 0; ks < 2; ++ks) {
      half8 a4[4], b4[4];
#pragma unroll
      for (int i = 0; i < 4; ++i)
        a4[i] = *(const half8*)&As[(wr2 * 64 + i * 16 + (lane & 15)) * bK + ks * 32 + (lane >> 4) * 8];
#pragma unroll
      for (int i = 0; i < 4; ++i)
        b4[i] = *(const half8*)&Bs[(wc2 * 64 + i * 16 + (lane & 15)) * bK + ks * 32 + (lane >> 4) * 8];
#pragma unroll
      for (int m = 0; m < 4; ++m)
#pragma unroll
        for (int n = 0; n < 4; ++n)
          acc[m][n] = __builtin_amdgcn_mfma_f32_16x16x32_f16(a4[m], b4[n], acc[m][n], 0, 0, 0);
    }
    __syncthreads();
  }
  float sc[4];
#pragma unroll
  for (int n = 0; n < 4; ++n) sc[n] = scale[bn0 + wc2 * 64 + n * 16 + (lane & 15)];
#pragma unroll
  for (int m = 0; m < 4; ++m) {
    const int row0 = bm0 + wr2 * 64 + m * 16 + (lane >> 4) * 4;
#pragma unroll
    for (int n = 0; n < 4; ++n) {
      const int col = bn0 + wc2 * 64 + n * 16 + (lane & 15);
#pragma unroll
      for (int i = 0; i < 4; ++i)
        Y[(size_t)(row0 + i) * Ndim + col] = (float)(_Float16)(acc[m][n][i] * sc[n]);
    }
  }
}

extern "C" void kernel_launch(void* const* d_in, const int* in_sizes, int n_in,
                              void* d_out, int out_size, void* d_ws, size_t ws_size,
                              hipStream_t stream) {
  const float* X = (const float*)d_in[0];
  const int* W32 = (const int*)d_in[1];
  const float* scale = (const float*)d_in[2];
  float* Y = (float*)d_out;

  const size_t wbytes = (size_t)Ndim * Kdim * sizeof(_Float16);  // 86 MiB
  const size_t xbytes = (size_t)Mdim * Kdim * sizeof(_Float16);  // 64 MiB

  if (ws_size >= wbytes + xbytes) {
    _Float16* Wh = (_Float16*)d_ws;
    _Float16* Xh = (_Float16*)((char*)d_ws + wbytes);
    conv_both<<<CONVB_TOT, 256, 0, stream>>>(W32, X, Wh, Xh);
    gemm8<<<NWG, 512, 0, stream>>>(Xh, Wh, scale, Y);
  } else {
    gemm_fused<<<(Ndim / 128) * (Mdim / 128), 256, 0, stream>>>(X, W32, scale, Y);
  }
}